// Round 1
// baseline (516.186 us; speedup 1.0000x reference)
//
#include <hip/hip_runtime.h>

// MoE top-1 layer, MI355X. N=8192 tokens, D=1024, F=4096, E=8.
// Only the selected expert's row is computed (68.7 GFLOP vs 550 dense).
// Gate in fp32 (must match reference argmax); expert GEMM in bf16 MFMA
// (threshold is 2% of max|ref| = 0.115; bf16 input rounding ~0.01).

#define N_TOKENS 8192
#define D_MODEL  1024
#define D_FF     4096
#define N_EXPERTS 8

#define BM 128
#define BN 128
#define BK 32
#define MT_MAX (N_TOKENS / BM + N_EXPERTS)   // 72 m-tiles worst case (per-expert BM padding)

typedef float  floatx4 __attribute__((ext_vector_type(4)));
typedef short  short8  __attribute__((ext_vector_type(8)));

__device__ __forceinline__ unsigned short f2bf(float f) {
    union { float f; unsigned u; } a; a.f = f;
    return (unsigned short)((a.u + 0x7fffu + ((a.u >> 16) & 1u)) >> 16); // RNE
}

// async global->LDS, 16B per lane. LDS dest = wave-uniform base + lane*16.
#define GLDS(gp, lp) __builtin_amdgcn_global_load_lds( \
    (const __attribute__((address_space(1))) unsigned int*)(const void*)(gp), \
    (__attribute__((address_space(3))) unsigned int*)(void*)(lp), 16, 0, 0)

// ---------------- init ----------------
__global__ void init_counts(int* counts) {
    if (threadIdx.x < N_EXPERTS) counts[threadIdx.x] = 0;
}

// -------- gate (fp32) + x -> bf16 conversion, fused --------
__global__ __launch_bounds__(64) void gate_kernel(
    const float* __restrict__ x, const float* __restrict__ gw,
    const float* __restrict__ gb, unsigned short* __restrict__ xb,
    int* __restrict__ top1, int* __restrict__ counts)
{
    int n = blockIdx.x;
    int l = threadIdx.x;
    const float4* xr = (const float4*)(x + (size_t)n * D_MODEL);
    float acc[N_EXPERTS];
#pragma unroll
    for (int e = 0; e < N_EXPERTS; ++e) acc[e] = 0.f;

#pragma unroll
    for (int j = 0; j < 4; ++j) {
        int d4 = j * 64 + l;          // float4 index within the row (0..255)
        float4 v = xr[d4];
        float vv[4] = { v.x, v.y, v.z, v.w };
#pragma unroll
        for (int t = 0; t < 4; ++t) {
            const float4* g = (const float4*)(gw + (size_t)(d4 * 4 + t) * N_EXPERTS);
            float4 g0 = g[0], g1 = g[1];
            acc[0] += vv[t] * g0.x; acc[1] += vv[t] * g0.y;
            acc[2] += vv[t] * g0.z; acc[3] += vv[t] * g0.w;
            acc[4] += vv[t] * g1.x; acc[5] += vv[t] * g1.y;
            acc[6] += vv[t] * g1.z; acc[7] += vv[t] * g1.w;
        }
        union { unsigned short us[4]; uint2 u; } pk;
        pk.us[0] = f2bf(v.x); pk.us[1] = f2bf(v.y);
        pk.us[2] = f2bf(v.z); pk.us[3] = f2bf(v.w);
        ((uint2*)(xb + (size_t)n * D_MODEL))[d4] = pk.u;
    }
#pragma unroll
    for (int e = 0; e < N_EXPERTS; ++e)
        for (int off = 32; off > 0; off >>= 1)
            acc[e] += __shfl_down(acc[e], off);
    if (l == 0) {
        float best = acc[0] + gb[0]; int be = 0;
#pragma unroll
        for (int e = 1; e < N_EXPERTS; ++e) {
            float v = acc[e] + gb[e];
            if (v > best) { best = v; be = e; }   // first-index tie-break, like argmax
        }
        top1[n] = be;
        atomicAdd(&counts[be], 1);
    }
}

// -------- expert_w [E][D][F] fp32 -> wt [E][F][D] bf16 (tiled transpose) --------
__global__ __launch_bounds__(256) void wconv_kernel(
    const float* __restrict__ w, unsigned short* __restrict__ wt)
{
    __shared__ unsigned short t[32][33];
    int e  = blockIdx.z;
    int f0 = blockIdx.x * 32;
    int d0 = blockIdx.y * 32;
    int tx = threadIdx.x, ty = threadIdx.y;
    const float* we = w + (size_t)e * D_MODEL * D_FF;
#pragma unroll
    for (int j = 0; j < 32; j += 8)
        t[ty + j][tx] = f2bf(we[(size_t)(d0 + ty + j) * D_FF + f0 + tx]);
    __syncthreads();
    unsigned short* wte = wt + (size_t)e * D_FF * D_MODEL;
#pragma unroll
    for (int j = 0; j < 32; j += 8)
        wte[(size_t)(f0 + ty + j) * D_MODEL + d0 + tx] = t[tx][ty + j];
}

// -------- scan: padded segment offsets + tile->expert map + list init --------
__global__ void scan_kernel(const int* __restrict__ counts, int* __restrict__ poff,
                            int* __restrict__ tile_expert, int* __restrict__ list,
                            int* __restrict__ cursor)
{
    if (threadIdx.x == 0) {
        int off = 0;
        for (int e = 0; e < N_EXPERTS; ++e) {
            poff[e] = off;
            int nt = (counts[e] + BM - 1) / BM;
            for (int t = 0; t < nt; ++t) tile_expert[off / BM + t] = e;
            off += nt * BM;
        }
        for (int t = off / BM; t < MT_MAX; ++t) tile_expert[t] = -1;
    }
    if (threadIdx.x < N_EXPERTS) cursor[threadIdx.x] = 0;
    for (int i = threadIdx.x; i < MT_MAX * BM; i += blockDim.x) list[i] = -1;
}

// -------- scatter tokens into per-expert lists --------
__global__ void scatter_kernel(const int* __restrict__ top1, const int* __restrict__ poff,
                               int* __restrict__ cursor, int* __restrict__ list)
{
    int n = blockIdx.x * 256 + threadIdx.x;
    if (n < N_TOKENS) {
        int e = top1[n];
        int slot = atomicAdd(&cursor[e], 1);
        list[poff[e] + slot] = n;
    }
}

// -------- grouped GEMM: out[tok][f] = xb[tok][:] . wt[e][f][:] + eb[e][f] --------
__global__ __launch_bounds__(256) void gemm_kernel(
    const unsigned short* __restrict__ xb,   // [N][D] bf16
    const unsigned short* __restrict__ wt,   // [E][F][D] bf16
    const float* __restrict__ eb,            // [E][F]
    const int* __restrict__ tile_expert,
    const int* __restrict__ list,
    float* __restrict__ out)                 // [N][F]
{
    int e = tile_expert[blockIdx.x];
    if (e < 0) return;
    int n0 = blockIdx.y * BN;

    __shared__ unsigned short As[BM * BK];   // 8 KB, no pad (global_load_lds)
    __shared__ unsigned short Bs[BN * BK];   // 8 KB
    __shared__ int toks[BM];

    int tid = threadIdx.x;
    int lane = tid & 63, wave = tid >> 6;
    if (tid < BM) toks[tid] = list[blockIdx.x * BM + tid];
    __syncthreads();

    // staging: 512 16B-chunks per tile; wave w issues chunks (w*2+i)*64+lane
    int c0 = (wave * 2 + 0) * 64 + lane;
    int c1 = (wave * 2 + 1) * 64 + lane;
    int ar0 = c0 >> 2, ac0 = (c0 & 3) * 8;
    int ar1 = c1 >> 2, ac1 = (c1 & 3) * 8;
    int ta0 = toks[ar0]; if (ta0 < 0) ta0 = 0;   // padding rows: load row 0, mask store
    int ta1 = toks[ar1]; if (ta1 < 0) ta1 = 0;
    const unsigned short* gA0 = xb + (size_t)ta0 * D_MODEL + ac0;
    const unsigned short* gA1 = xb + (size_t)ta1 * D_MODEL + ac1;
    const unsigned short* wbase = wt + (size_t)e * D_FF * D_MODEL;
    const unsigned short* gB0 = wbase + (size_t)(n0 + ar0) * D_MODEL + ac0;
    const unsigned short* gB1 = wbase + (size_t)(n0 + ar1) * D_MODEL + ac1;
    unsigned short* lA0 = As + (wave * 2 + 0) * 512;   // 1024 B per instr, wave-uniform
    unsigned short* lA1 = As + (wave * 2 + 1) * 512;
    unsigned short* lB0 = Bs + (wave * 2 + 0) * 512;
    unsigned short* lB1 = Bs + (wave * 2 + 1) * 512;

    floatx4 acc[4][4];
#pragma unroll
    for (int mi = 0; mi < 4; ++mi)
#pragma unroll
        for (int ni = 0; ni < 4; ++ni)
            acc[mi][ni] = (floatx4){0.f, 0.f, 0.f, 0.f};

    int mw = (wave >> 1) * 64;
    int nw = (wave & 1) * 64;
    int q = lane >> 4, r = lane & 15;

    for (int k0 = 0; k0 < D_MODEL; k0 += BK) {
        GLDS(gA0 + k0, lA0);
        GLDS(gA1 + k0, lA1);
        GLDS(gB0 + k0, lB0);
        GLDS(gB1 + k0, lB1);
        __syncthreads();

        short8 af[4], bf[4];
#pragma unroll
        for (int mi = 0; mi < 4; ++mi)
            af[mi] = *(const short8*)&As[(mw + mi * 16 + r) * BK + q * 8];
#pragma unroll
        for (int ni = 0; ni < 4; ++ni)
            bf[ni] = *(const short8*)&Bs[(nw + ni * 16 + r) * BK + q * 8];
#pragma unroll
        for (int mi = 0; mi < 4; ++mi)
#pragma unroll
            for (int ni = 0; ni < 4; ++ni)
                acc[mi][ni] = __builtin_amdgcn_mfma_f32_16x16x32_bf16(
                    af[mi], bf[ni], acc[mi][ni], 0, 0, 0);
        __syncthreads();
    }

    // epilogue: C/D layout col=lane&15, row=(lane>>4)*4+i  [m89-verified]
#pragma unroll
    for (int ni = 0; ni < 4; ++ni) {
        int f = n0 + nw + ni * 16 + r;
        float bias = eb[(size_t)e * D_FF + f];
#pragma unroll
        for (int mi = 0; mi < 4; ++mi) {
            int mbase = mw + mi * 16 + q * 4;
#pragma unroll
            for (int i = 0; i < 4; ++i) {
                int tok = toks[mbase + i];
                if (tok >= 0) out[(size_t)tok * D_FF + f] = acc[mi][ni][i] + bias;
            }
        }
    }
}

extern "C" void kernel_launch(void* const* d_in, const int* in_sizes, int n_in,
                              void* d_out, int out_size, void* d_ws, size_t ws_size,
                              hipStream_t stream) {
    const float* x  = (const float*)d_in[0];
    const float* gw = (const float*)d_in[1];
    const float* gb = (const float*)d_in[2];
    const float* ew = (const float*)d_in[3];
    const float* eb = (const float*)d_in[4];
    float* out = (float*)d_out;

    char* ws = (char*)d_ws;
    int* top1        = (int*)ws;                    // 32 KB
    int* counts      = (int*)(ws + 32768);
    int* cursor      = (int*)(ws + 32768 + 64);
    int* poff        = (int*)(ws + 32768 + 128);
    int* tile_expert = (int*)(ws + 32768 + 256);    // 288 B
    int* list        = (int*)(ws + 36864);          // 72*128*4 = 36864 B
    unsigned short* xb = (unsigned short*)(ws + 131072);                          // 16.8 MB
    unsigned short* wt = (unsigned short*)(ws + 131072 + (size_t)N_TOKENS * D_MODEL * 2); // 67 MB

    hipLaunchKernelGGL(init_counts, dim3(1), dim3(64), 0, stream, counts);
    hipLaunchKernelGGL(gate_kernel, dim3(N_TOKENS), dim3(64), 0, stream,
                       x, gw, gb, xb, top1, counts);
    hipLaunchKernelGGL(wconv_kernel, dim3(D_FF / 32, D_MODEL / 32, N_EXPERTS), dim3(32, 8),
                       0, stream, ew, wt);
    hipLaunchKernelGGL(scan_kernel, dim3(1), dim3(256), 0, stream,
                       counts, poff, tile_expert, list, cursor);
    hipLaunchKernelGGL(scatter_kernel, dim3(N_TOKENS / 256), dim3(256), 0, stream,
                       top1, poff, cursor, list);
    hipLaunchKernelGGL(gemm_kernel, dim3(MT_MAX, D_FF / BN), dim3(256), 0, stream,
                       xb, wt, eb, tile_expert, list, out);
}

// Round 2
// 504.361 us; speedup vs baseline: 1.0234x; 1.0234x over previous
//
#include <hip/hip_runtime.h>

// MoE top-1 layer, MI355X. N=8192 tokens, D=1024, F=4096, E=8.
// R2: vectorized wconv (was scalar-LDS bound), dbuf single-barrier GEMM,
// XCD swizzle, ballot-aggregated scatter.

#define N_TOKENS 8192
#define D_MODEL  1024
#define D_FF     4096
#define N_EXPERTS 8

#define BM 128
#define BN 128
#define BK 32
#define NKT (D_MODEL / BK)                   // 32 k-iterations
#define MT_MAX (N_TOKENS / BM + N_EXPERTS)   // 72 m-tiles worst case
#define NTILES (D_FF / BN)                   // 32 n-tiles

typedef float  floatx4 __attribute__((ext_vector_type(4)));
typedef short  short8  __attribute__((ext_vector_type(8)));

__device__ __forceinline__ unsigned short f2bf(float f) {
    union { float f; unsigned u; } a; a.f = f;
    return (unsigned short)((a.u + 0x7fffu + ((a.u >> 16) & 1u)) >> 16); // RNE
}

// async global->LDS, 16B per lane. Global addr per-lane; LDS dest wave-uniform base + lane*16.
#define GLDS(gp, lp) __builtin_amdgcn_global_load_lds( \
    (const __attribute__((address_space(1))) unsigned int*)(const void*)(gp), \
    (__attribute__((address_space(3))) unsigned int*)(void*)(lp), 16, 0, 0)

// ---------------- init ----------------
__global__ void init_counts(int* counts) {
    if (threadIdx.x < N_EXPERTS) counts[threadIdx.x] = 0;
}

// -------- gate (fp32) + x -> bf16 conversion, fused; 1 wave per token --------
__global__ __launch_bounds__(256) void gate_kernel(
    const float* __restrict__ x, const float* __restrict__ gw,
    const float* __restrict__ gb, unsigned short* __restrict__ xb,
    int* __restrict__ top1, int* __restrict__ counts)
{
    int wave = threadIdx.x >> 6;
    int l    = threadIdx.x & 63;
    int n = blockIdx.x * 4 + wave;
    const float4* xr = (const float4*)(x + (size_t)n * D_MODEL);
    float acc[N_EXPERTS];
#pragma unroll
    for (int e = 0; e < N_EXPERTS; ++e) acc[e] = 0.f;

#pragma unroll
    for (int j = 0; j < 4; ++j) {
        int d4 = j * 64 + l;          // float4 index within the row (0..255)
        float4 v = xr[d4];
        float vv[4] = { v.x, v.y, v.z, v.w };
#pragma unroll
        for (int t = 0; t < 4; ++t) {
            const float4* g = (const float4*)(gw + (size_t)(d4 * 4 + t) * N_EXPERTS);
            float4 g0 = g[0], g1 = g[1];
            acc[0] += vv[t] * g0.x; acc[1] += vv[t] * g0.y;
            acc[2] += vv[t] * g0.z; acc[3] += vv[t] * g0.w;
            acc[4] += vv[t] * g1.x; acc[5] += vv[t] * g1.y;
            acc[6] += vv[t] * g1.z; acc[7] += vv[t] * g1.w;
        }
        union { unsigned short us[4]; uint2 u; } pk;
        pk.us[0] = f2bf(v.x); pk.us[1] = f2bf(v.y);
        pk.us[2] = f2bf(v.z); pk.us[3] = f2bf(v.w);
        ((uint2*)(xb + (size_t)n * D_MODEL))[d4] = pk.u;
    }
#pragma unroll
    for (int e = 0; e < N_EXPERTS; ++e)
        for (int off = 32; off > 0; off >>= 1)
            acc[e] += __shfl_down(acc[e], off);
    if (l == 0) {
        float best = acc[0] + gb[0]; int be = 0;
#pragma unroll
        for (int e = 1; e < N_EXPERTS; ++e) {
            float v = acc[e] + gb[e];
            if (v > best) { best = v; be = e; }   // first-index tie-break
        }
        top1[n] = be;
        atomicAdd(&counts[be], 1);
    }
}

// -------- expert_w [E][D][F] fp32 -> wt [E][F][D] bf16 --------
// 64x64 tile: register 4x4 transpose + vector LDS both ways; dwordx4 stores.
#define WST 68   // LDS row stride in shorts: 136 B, 8-byte aligned rows
__global__ __launch_bounds__(256) void wconv_kernel(
    const float* __restrict__ w, unsigned short* __restrict__ wt)
{
    __shared__ unsigned short tt[64 * WST];   // 8704 B, layout [f][d]
    int e  = blockIdx.z;
    int f0 = blockIdx.x * 64;
    int d0 = blockIdx.y * 64;
    int t  = threadIdx.x;
    const float* we = w + (size_t)e * D_MODEL * D_FF + (size_t)d0 * D_FF + f0;

    int fg = (t & 15) * 4;    // f within tile (thread's 4 columns)
    int dg = (t >> 4) * 4;    // d within tile (thread's 4 rows)
    unsigned short v[4][4];   // v[fi][dj]
#pragma unroll
    for (int j = 0; j < 4; ++j) {
        float4 r = *(const float4*)(we + (size_t)(dg + j) * D_FF + fg);
        v[0][j] = f2bf(r.x); v[1][j] = f2bf(r.y);
        v[2][j] = f2bf(r.z); v[3][j] = f2bf(r.w);
    }
#pragma unroll
    for (int i = 0; i < 4; ++i) {
        union { unsigned short us[4]; uint2 u; } pk;
        pk.us[0] = v[i][0]; pk.us[1] = v[i][1];
        pk.us[2] = v[i][2]; pk.us[3] = v[i][3];
        *(uint2*)&tt[(fg + i) * WST + dg] = pk.u;    // b64 write along d
    }
    __syncthreads();

    unsigned short* wte = wt + (size_t)e * D_FF * D_MODEL + (size_t)f0 * D_MODEL + d0;
    int fr = t >> 3;          // 0..31 (two passes -> 64 f-rows)
    int dr = (t & 7) * 8;     // 8 lanes x 16B = 128B contiguous stores
#pragma unroll
    for (int p = 0; p < 2; ++p) {
        int f = fr + p * 32;
        uint2 a = *(const uint2*)&tt[f * WST + dr];
        uint2 b = *(const uint2*)&tt[f * WST + dr + 4];
        uint4 o; o.x = a.x; o.y = a.y; o.z = b.x; o.w = b.y;
        *(uint4*)(wte + (size_t)f * D_MODEL + dr) = o;
    }
}

// -------- scan: padded segment offsets + tile->expert map + list init --------
__global__ void scan_kernel(const int* __restrict__ counts, int* __restrict__ poff,
                            int* __restrict__ tile_expert, int* __restrict__ list,
                            int* __restrict__ cursor)
{
    if (threadIdx.x == 0) {
        int off = 0;
        for (int e = 0; e < N_EXPERTS; ++e) {
            poff[e] = off;
            int nt = (counts[e] + BM - 1) / BM;
            for (int t = 0; t < nt; ++t) tile_expert[off / BM + t] = e;
            off += nt * BM;
        }
        for (int t = off / BM; t < MT_MAX; ++t) tile_expert[t] = -1;
    }
    if (threadIdx.x < N_EXPERTS) cursor[threadIdx.x] = 0;
    for (int i = threadIdx.x; i < MT_MAX * BM; i += blockDim.x) list[i] = -1;
}

// -------- scatter: ballot-aggregated atomics (8 per wave, not 64) --------
__global__ __launch_bounds__(256) void scatter_kernel(
    const int* __restrict__ top1, const int* __restrict__ poff,
    int* __restrict__ cursor, int* __restrict__ list)
{
    int n = blockIdx.x * 256 + threadIdx.x;
    int l = threadIdx.x & 63;
    int e = top1[n];
    int slot = 0;
#pragma unroll
    for (int e0 = 0; e0 < N_EXPERTS; ++e0) {
        unsigned long long m = __ballot(e == e0);
        if (e == e0) {
            int leader = __ffsll((unsigned long long)m) - 1;
            int base = 0;
            if (l == leader) base = atomicAdd(&cursor[e0], __popcll(m));
            base = __shfl(base, leader);
            slot = base + __popcll(m & ((1ull << l) - 1ull));
        }
    }
    list[poff[e] + slot] = n;
}

// -------- grouped GEMM, double-buffered LDS, one barrier per k-iter --------
__global__ __launch_bounds__(256) void gemm_kernel(
    const unsigned short* __restrict__ xb,   // [N][D] bf16
    const unsigned short* __restrict__ wt,   // [E][F][D] bf16
    const float* __restrict__ eb,            // [E][F]
    const int* __restrict__ tile_expert,
    const int* __restrict__ list,
    float* __restrict__ out)                 // [N][F]
{
    // XCD swizzle: each XCD (bid&7) owns 4 n-tiles; m advances within XCD.
    int bid = blockIdx.x;
    int xcd = bid & 7, w = bid >> 3;
    int mt  = w >> 2;
    int nt  = (xcd << 2) | (w & 3);
    int e = tile_expert[mt];
    if (e < 0) return;
    int n0 = nt * BN;

    __shared__ unsigned short As[2][BM * BK];   // 2 x 8 KB
    __shared__ unsigned short Bs[2][BN * BK];   // 2 x 8 KB
    __shared__ int toks[BM];

    int tid = threadIdx.x;
    int lane = tid & 63, wave = tid >> 6;
    if (tid < BM) toks[tid] = list[mt * BM + tid];
    __syncthreads();

    // staging: 512 16B-chunks per tile; wave w issues chunks (w*2+i)*64+lane
    int c0 = (wave * 2 + 0) * 64 + lane;
    int c1 = (wave * 2 + 1) * 64 + lane;
    int ar0 = c0 >> 2, ac0 = (c0 & 3) * 8;
    int ar1 = c1 >> 2, ac1 = (c1 & 3) * 8;
    int ta0 = toks[ar0]; if (ta0 < 0) ta0 = 0;
    int ta1 = toks[ar1]; if (ta1 < 0) ta1 = 0;
    const unsigned short* gA0 = xb + (size_t)ta0 * D_MODEL + ac0;
    const unsigned short* gA1 = xb + (size_t)ta1 * D_MODEL + ac1;
    const unsigned short* wbase = wt + (size_t)e * D_FF * D_MODEL;
    const unsigned short* gB0 = wbase + (size_t)(n0 + ar0) * D_MODEL + ac0;
    const unsigned short* gB1 = wbase + (size_t)(n0 + ar1) * D_MODEL + ac1;
    int o0 = (wave * 2 + 0) * 512;   // LDS offsets (shorts), wave-uniform
    int o1 = (wave * 2 + 1) * 512;

    floatx4 acc[4][4];
#pragma unroll
    for (int mi = 0; mi < 4; ++mi)
#pragma unroll
        for (int ni = 0; ni < 4; ++ni)
            acc[mi][ni] = (floatx4){0.f, 0.f, 0.f, 0.f};

    int mw = (wave >> 1) * 64;
    int nw = (wave & 1) * 64;
    int q = lane >> 4, r = lane & 15;

    // preload k-tile 0 into buffer 0
    GLDS(gA0, &As[0][o0]);
    GLDS(gA1, &As[0][o1]);
    GLDS(gB0, &Bs[0][o0]);
    GLDS(gB1, &Bs[0][o1]);

    for (int kt = 0; kt < NKT; ++kt) {
        int cur = kt & 1;
        __syncthreads();   // drains vmcnt (prefetch done) + protects prev buffer reads
        if (kt + 1 < NKT) {
            int k1 = (kt + 1) * BK;
            GLDS(gA0 + k1, &As[cur ^ 1][o0]);
            GLDS(gA1 + k1, &As[cur ^ 1][o1]);
            GLDS(gB0 + k1, &Bs[cur ^ 1][o0]);
            GLDS(gB1 + k1, &Bs[cur ^ 1][o1]);
        }
        short8 af[4], bf[4];
#pragma unroll
        for (int mi = 0; mi < 4; ++mi)
            af[mi] = *(const short8*)&As[cur][(mw + mi * 16 + r) * BK + q * 8];
#pragma unroll
        for (int ni = 0; ni < 4; ++ni)
            bf[ni] = *(const short8*)&Bs[cur][(nw + ni * 16 + r) * BK + q * 8];
#pragma unroll
        for (int mi = 0; mi < 4; ++mi)
#pragma unroll
            for (int ni = 0; ni < 4; ++ni)
                acc[mi][ni] = __builtin_amdgcn_mfma_f32_16x16x32_bf16(
                    af[mi], bf[ni], acc[mi][ni], 0, 0, 0);
    }

    // epilogue: C/D layout col=lane&15, row=(lane>>4)*4+i  [m89-verified]
#pragma unroll
    for (int ni = 0; ni < 4; ++ni) {
        int f = n0 + nw + ni * 16 + r;
        float bias = eb[(size_t)e * D_FF + f];
#pragma unroll
        for (int mi = 0; mi < 4; ++mi) {
            int mbase = mw + mi * 16 + q * 4;
#pragma unroll
            for (int i = 0; i < 4; ++i) {
                int tok = toks[mbase + i];
                if (tok >= 0) out[(size_t)tok * D_FF + f] = acc[mi][ni][i] + bias;
            }
        }
    }
}

extern "C" void kernel_launch(void* const* d_in, const int* in_sizes, int n_in,
                              void* d_out, int out_size, void* d_ws, size_t ws_size,
                              hipStream_t stream) {
    const float* x  = (const float*)d_in[0];
    const float* gw = (const float*)d_in[1];
    const float* gb = (const float*)d_in[2];
    const float* ew = (const float*)d_in[3];
    const float* eb = (const float*)d_in[4];
    float* out = (float*)d_out;

    char* ws = (char*)d_ws;
    int* top1        = (int*)ws;                    // 32 KB
    int* counts      = (int*)(ws + 32768);
    int* cursor      = (int*)(ws + 32768 + 64);
    int* poff        = (int*)(ws + 32768 + 128);
    int* tile_expert = (int*)(ws + 32768 + 256);
    int* list        = (int*)(ws + 36864);          // 72*128*4 = 36864 B
    unsigned short* xb = (unsigned short*)(ws + 131072);                          // 16.8 MB
    unsigned short* wt = (unsigned short*)(ws + 131072 + (size_t)N_TOKENS * D_MODEL * 2); // 67 MB

    hipLaunchKernelGGL(init_counts, dim3(1), dim3(64), 0, stream, counts);
    hipLaunchKernelGGL(gate_kernel, dim3(N_TOKENS / 4), dim3(256), 0, stream,
                       x, gw, gb, xb, top1, counts);
    hipLaunchKernelGGL(wconv_kernel, dim3(D_FF / 64, D_MODEL / 64, N_EXPERTS), dim3(256),
                       0, stream, ew, wt);
    hipLaunchKernelGGL(scan_kernel, dim3(1), dim3(256), 0, stream,
                       counts, poff, tile_expert, list, cursor);
    hipLaunchKernelGGL(scatter_kernel, dim3(N_TOKENS / 256), dim3(256), 0, stream,
                       top1, poff, cursor, list);
    hipLaunchKernelGGL(gemm_kernel, dim3(MT_MAX * NTILES), dim3(256), 0, stream,
                       xb, wt, eb, tile_expert, list, out);
}

// Round 3
// 439.727 us; speedup vs baseline: 1.1739x; 1.1470x over previous
//
#include <hip/hip_runtime.h>

// MoE top-1 layer, MI355X. N=8192 tokens, D=1024, F=4096, E=8.
// R3: 3 launches (prep = gate ∪ wconv, route = histogram+scan+scatter, gemm).
// GEMM: BK=64 single-buffer (16 k-iters, half the barrier drains) +
// XOR-swizzled LDS chunk placement (breaks 8-way ds_read_b128 conflicts;
// GLDS forbids padding but chunk->lane permutation is free).

#define N_TOKENS 8192
#define D_MODEL  1024
#define D_FF     4096
#define N_EXPERTS 8

#define BM 128
#define BN 128
#define BK 64
#define NKT (D_MODEL / BK)                   // 16 k-iterations
#define MT_MAX (N_TOKENS / BM + N_EXPERTS)   // 72 m-tiles worst case
#define NTILES (D_FF / BN)                   // 32 n-tiles
#define GATE_BLOCKS (N_TOKENS / 4)           // 2048
#define WCONV_BLOCKS ((D_FF / 64) * (D_MODEL / 64) * N_EXPERTS)  // 8192

typedef float  floatx4 __attribute__((ext_vector_type(4)));
typedef short  short8  __attribute__((ext_vector_type(8)));

__device__ __forceinline__ unsigned short f2bf(float f) {
    union { float f; unsigned u; } a; a.f = f;
    return (unsigned short)((a.u + 0x7fffu + ((a.u >> 16) & 1u)) >> 16); // RNE
}

#define GLDS(gp, lp) __builtin_amdgcn_global_load_lds( \
    (const __attribute__((address_space(1))) unsigned int*)(const void*)(gp), \
    (__attribute__((address_space(3))) unsigned int*)(void*)(lp), 16, 0, 0)

// -------- prep: gate (fp32, writes top1 + xb) ∪ wconv (ew -> wt bf16 [E][F][D]) --------
#define WST 68
__global__ __launch_bounds__(256) void prep_kernel(
    const float* __restrict__ x, const float* __restrict__ gw,
    const float* __restrict__ gb, const float* __restrict__ ew,
    unsigned short* __restrict__ xb, unsigned short* __restrict__ wt,
    int* __restrict__ top1)
{
    if (blockIdx.x < GATE_BLOCKS) {
        int wave = threadIdx.x >> 6;
        int l    = threadIdx.x & 63;
        int n = blockIdx.x * 4 + wave;
        const float4* xr = (const float4*)(x + (size_t)n * D_MODEL);
        float acc[N_EXPERTS];
#pragma unroll
        for (int e = 0; e < N_EXPERTS; ++e) acc[e] = 0.f;
#pragma unroll
        for (int j = 0; j < 4; ++j) {
            int d4 = j * 64 + l;
            float4 v = xr[d4];
            float vv[4] = { v.x, v.y, v.z, v.w };
#pragma unroll
            for (int t = 0; t < 4; ++t) {
                const float4* g = (const float4*)(gw + (size_t)(d4 * 4 + t) * N_EXPERTS);
                float4 g0 = g[0], g1 = g[1];
                acc[0] += vv[t] * g0.x; acc[1] += vv[t] * g0.y;
                acc[2] += vv[t] * g0.z; acc[3] += vv[t] * g0.w;
                acc[4] += vv[t] * g1.x; acc[5] += vv[t] * g1.y;
                acc[6] += vv[t] * g1.z; acc[7] += vv[t] * g1.w;
            }
            union { unsigned short us[4]; uint2 u; } pk;
            pk.us[0] = f2bf(v.x); pk.us[1] = f2bf(v.y);
            pk.us[2] = f2bf(v.z); pk.us[3] = f2bf(v.w);
            ((uint2*)(xb + (size_t)n * D_MODEL))[d4] = pk.u;
        }
#pragma unroll
        for (int e = 0; e < N_EXPERTS; ++e)
            for (int off = 32; off > 0; off >>= 1)
                acc[e] += __shfl_down(acc[e], off);
        if (l == 0) {
            float best = acc[0] + gb[0]; int be = 0;
#pragma unroll
            for (int e = 1; e < N_EXPERTS; ++e) {
                float v = acc[e] + gb[e];
                if (v > best) { best = v; be = e; }
            }
            top1[n] = be;
        }
    } else {
        __shared__ unsigned short tt[64 * WST];
        int b  = blockIdx.x - GATE_BLOCKS;
        int f0 = (b & 63) * 64;
        int d0 = ((b >> 6) & 15) * 64;
        int e  = b >> 10;
        int t  = threadIdx.x;
        const float* we = ew + (size_t)e * D_MODEL * D_FF + (size_t)d0 * D_FF + f0;
        int fg = (t & 15) * 4;
        int dg = (t >> 4) * 4;
        unsigned short v[4][4];
#pragma unroll
        for (int j = 0; j < 4; ++j) {
            float4 r = *(const float4*)(we + (size_t)(dg + j) * D_FF + fg);
            v[0][j] = f2bf(r.x); v[1][j] = f2bf(r.y);
            v[2][j] = f2bf(r.z); v[3][j] = f2bf(r.w);
        }
#pragma unroll
        for (int i = 0; i < 4; ++i) {
            union { unsigned short us[4]; uint2 u; } pk;
            pk.us[0] = v[i][0]; pk.us[1] = v[i][1];
            pk.us[2] = v[i][2]; pk.us[3] = v[i][3];
            *(uint2*)&tt[(fg + i) * WST + dg] = pk.u;
        }
        __syncthreads();
        unsigned short* wte = wt + (size_t)e * D_FF * D_MODEL + (size_t)f0 * D_MODEL + d0;
        int fr = t >> 3;
        int dr = (t & 7) * 8;
#pragma unroll
        for (int p = 0; p < 2; ++p) {
            int f = fr + p * 32;
            uint2 a = *(const uint2*)&tt[f * WST + dr];
            uint2 c = *(const uint2*)&tt[f * WST + dr + 4];
            uint4 o; o.x = a.x; o.y = a.y; o.z = c.x; o.w = c.y;
            *(uint4*)(wte + (size_t)f * D_MODEL + dr) = o;
        }
    }
}

// -------- route: single block, histogram + scan + order-preserving scatter --------
__global__ __launch_bounds__(1024) void route_kernel(
    const int* __restrict__ top1, int* __restrict__ tile_expert, int* __restrict__ list)
{
    __shared__ int wtot[16][N_EXPERTS];
    __shared__ int wbase[16][N_EXPERTS];
    __shared__ int pofs[N_EXPERTS];
    int t = threadIdx.x, wv = t >> 6, l = t & 63;

    for (int i = t; i < MT_MAX * BM; i += 1024) list[i] = -1;

    int e8[8];
    const int4* tp = (const int4*)(top1 + t * 8);
    int4 a = tp[0], b = tp[1];
    e8[0] = a.x; e8[1] = a.y; e8[2] = a.z; e8[3] = a.w;
    e8[4] = b.x; e8[5] = b.y; e8[6] = b.z; e8[7] = b.w;
    int c[N_EXPERTS], s[N_EXPERTS];
#pragma unroll
    for (int e = 0; e < N_EXPERTS; ++e) c[e] = 0;
#pragma unroll
    for (int j = 0; j < 8; ++j) c[e8[j]]++;
#pragma unroll
    for (int e = 0; e < N_EXPERTS; ++e) s[e] = c[e];
    for (int off = 1; off < 64; off <<= 1) {
#pragma unroll
        for (int e = 0; e < N_EXPERTS; ++e) {
            int v = __shfl_up(s[e], off);
            if (l >= off) s[e] += v;
        }
    }
    if (l == 63)
#pragma unroll
        for (int e = 0; e < N_EXPERTS; ++e) wtot[wv][e] = s[e];
    __syncthreads();
    if (t == 0) {
        int cnt[N_EXPERTS];
        for (int e = 0; e < N_EXPERTS; ++e) {
            cnt[e] = 0;
            for (int w = 0; w < 16; ++w) { wbase[w][e] = cnt[e]; cnt[e] += wtot[w][e]; }
        }
        int off = 0;
        for (int e = 0; e < N_EXPERTS; ++e) {
            pofs[e] = off;
            int ntl = (cnt[e] + BM - 1) / BM;
            for (int k = 0; k < ntl; ++k) tile_expert[off / BM + k] = e;
            off += ntl * BM;
        }
        for (int k = off / BM; k < MT_MAX; ++k) tile_expert[k] = -1;
    }
    __syncthreads();
    int base[N_EXPERTS];
#pragma unroll
    for (int e = 0; e < N_EXPERTS; ++e) base[e] = pofs[e] + wbase[wv][e] + s[e] - c[e];
#pragma unroll
    for (int j = 0; j < 8; ++j) {
        int e = e8[j];
        list[base[e]++] = t * 8 + j;
    }
}

// -------- grouped GEMM: BK=64, single buffer, XOR-swizzled LDS --------
__global__ __launch_bounds__(256) void gemm_kernel(
    const unsigned short* __restrict__ xb,   // [N][D] bf16
    const unsigned short* __restrict__ wt,   // [E][F][D] bf16
    const float* __restrict__ eb,            // [E][F]
    const int* __restrict__ tile_expert,
    const int* __restrict__ list,
    float* __restrict__ out)                 // [N][F]
{
    int bid = blockIdx.x;
    int xcd = bid & 7, w = bid >> 3;
    int mt  = w >> 2;
    int nt  = (xcd << 2) | (w & 3);
    int e = tile_expert[mt];
    if (e < 0) return;
    int n0 = nt * BN;

    __shared__ unsigned short As[BM * BK];   // 16 KB
    __shared__ unsigned short Bs[BN * BK];   // 16 KB
    __shared__ int toks[BM];

    int tid = threadIdx.x;
    int lane = tid & 63, wave = tid >> 6;
    if (tid < BM) toks[tid] = list[mt * BM + tid];
    __syncthreads();

    // staging: 1024 16B-chunks per tile, 4 GLDS/thread each for A and B.
    // LDS slot s holds logical chunk (row = s>>3, c8 = (s&7) ^ (row&7)).
    const unsigned short* gA[4];
    const unsigned short* gB[4];
    const unsigned short* wbase = wt + (size_t)e * D_FF * D_MODEL;
#pragma unroll
    for (int i = 0; i < 4; ++i) {
        int s = wave * 256 + i * 64 + lane;
        int row = s >> 3, c8 = (s & 7) ^ (row & 7);
        int ta = toks[row]; if (ta < 0) ta = 0;
        gA[i] = xb + (size_t)ta * D_MODEL + c8 * 8;
        gB[i] = wbase + (size_t)(n0 + row) * D_MODEL + c8 * 8;
    }

    floatx4 acc[4][4];
#pragma unroll
    for (int mi = 0; mi < 4; ++mi)
#pragma unroll
        for (int ni = 0; ni < 4; ++ni)
            acc[mi][ni] = (floatx4){0.f, 0.f, 0.f, 0.f};

    int mw = (wave >> 1) * 64;
    int nw = (wave & 1) * 64;
    int q = lane >> 4, r = lane & 15;
    int xr = r & 7;
    int ra[4], rb[4];
#pragma unroll
    for (int i = 0; i < 4; ++i) { ra[i] = (mw + i * 16 + r) * 8; rb[i] = (nw + i * 16 + r) * 8; }

    for (int kt = 0; kt < NKT; ++kt) {
        int k0 = kt * BK;
#pragma unroll
        for (int i = 0; i < 4; ++i) GLDS(gA[i] + k0, &As[(wave * 256 + i * 64) * 8]);
#pragma unroll
        for (int i = 0; i < 4; ++i) GLDS(gB[i] + k0, &Bs[(wave * 256 + i * 64) * 8]);
        __syncthreads();
#pragma unroll
        for (int ks = 0; ks < 2; ++ks) {
            int cq = (ks * 4 + q) ^ xr;
            short8 af[4], bf[4];
#pragma unroll
            for (int mi = 0; mi < 4; ++mi)
                af[mi] = *(const short8*)&As[(ra[mi] + cq) * 8];
#pragma unroll
            for (int ni = 0; ni < 4; ++ni)
                bf[ni] = *(const short8*)&Bs[(rb[ni] + cq) * 8];
#pragma unroll
            for (int mi = 0; mi < 4; ++mi)
#pragma unroll
                for (int ni = 0; ni < 4; ++ni)
                    acc[mi][ni] = __builtin_amdgcn_mfma_f32_16x16x32_bf16(
                        af[mi], bf[ni], acc[mi][ni], 0, 0, 0);
        }
        __syncthreads();
    }

    // epilogue: C/D layout col=lane&15, row=(lane>>4)*4+i  [m89-verified]
#pragma unroll
    for (int ni = 0; ni < 4; ++ni) {
        int f = n0 + nw + ni * 16 + r;
        float bias = eb[(size_t)e * D_FF + f];
#pragma unroll
        for (int mi = 0; mi < 4; ++mi) {
            int mbase = mw + mi * 16 + q * 4;
#pragma unroll
            for (int i = 0; i < 4; ++i) {
                int tok = toks[mbase + i];
                if (tok >= 0) out[(size_t)tok * D_FF + f] = acc[mi][ni][i] + bias;
            }
        }
    }
}

extern "C" void kernel_launch(void* const* d_in, const int* in_sizes, int n_in,
                              void* d_out, int out_size, void* d_ws, size_t ws_size,
                              hipStream_t stream) {
    const float* x  = (const float*)d_in[0];
    const float* gw = (const float*)d_in[1];
    const float* gb = (const float*)d_in[2];
    const float* ew = (const float*)d_in[3];
    const float* eb = (const float*)d_in[4];
    float* out = (float*)d_out;

    char* ws = (char*)d_ws;
    int* top1        = (int*)ws;                    // 32 KB
    int* tile_expert = (int*)(ws + 32768);          // 288 B
    int* list        = (int*)(ws + 36864);          // 72*128*4 = 36864 B
    unsigned short* xb = (unsigned short*)(ws + 131072);                          // 16.8 MB
    unsigned short* wt = (unsigned short*)(ws + 131072 + (size_t)N_TOKENS * D_MODEL * 2); // 67 MB

    hipLaunchKernelGGL(prep_kernel, dim3(GATE_BLOCKS + WCONV_BLOCKS), dim3(256), 0, stream,
                       x, gw, gb, ew, xb, wt, top1);
    hipLaunchKernelGGL(route_kernel, dim3(1), dim3(1024), 0, stream,
                       top1, tile_expert, list);
    hipLaunchKernelGGL(gemm_kernel, dim3(MT_MAX * NTILES), dim3(256), 0, stream,
                       xb, wt, eb, tile_expert, list, out);
}